// Round 4
// baseline (875.576 us; speedup 1.0000x reference)
//
#include <hip/hip_runtime.h>

constexpr int TN     = 100000;
constexpr int CHUNKS = 1000;
constexpr int GROUPS = 100;
constexpr int CGRP   = 10;     // chunks per group; GROUPS*CGRP == CHUNKS

constexpr float LOG2E = 1.4426950408889634f;

// float offsets into ws (static region)
constexpr size_t OFF_W   = 0;      // 32x32
constexpr size_t OFF_W2  = 1024;   // 32x32
constexpr size_t OFF_I2V = 2048;   // 32  (i2v * LOG2E)
constexpr size_t OFF_LB  = 2112;   // 64  loss buckets
constexpr size_t OFF_XG  = 2176;   // GROUPS*32 group-start states
constexpr size_t OFF_QS  = 8192;   // SUB*1024 subchunk matrices, then qc/r/e0

// ---------------------------------------------------------------------------
// Prep (1 block, 256 thr): W[i][j] = aij*A_j*B_ij, W2 = W*A_j*B_ij, i2v*LOG2E
// ---------------------------------------------------------------------------
__global__ __launch_bounds__(256) void k_prep(
    const float* __restrict__ mean, const float* __restrict__ var,
    const float* __restrict__ bate_p, const float* __restrict__ aij,
    float* __restrict__ ws)
{
  const int tid = threadIdx.x;
  const int j = tid & 31, ig = tid >> 5;
  float vj   = var[j];
  float i2v  = 0.5f / vj;
  float norm = rsqrtf(2.0f * 3.1415926f * vj);
  float Aj   = norm * expf(mean[j] * i2v);
  float bate = bate_p[0];
  if (tid < 32) ws[OFF_I2V + tid] = i2v * LOG2E;
#pragma unroll
  for (int m = 0; m < 4; ++m) {
    int i = ig * 4 + m;
    float Bij = expf(-bate * mean[i] * i2v);
    float w = aij[i * 32 + j] * Aj * Bij;
    ws[OFF_W  + i * 32 + j] = w;
    ws[OFF_W2 + i * 32 + j] = w * Aj * Bij;
  }
}

// ---------------------------------------------------------------------------
// Phase 1: 4 waves/block, each wave owns ONE subchunk in a private LDS slice.
// Wave-lockstep => no barriers, single Q buffer (reads precede writes in
// program order for the whole wave). Lane (jt,it): 4x4 tile, W cols in VGPRs.
// Q_new[j,i] = u_j * sum_k W[k,j] * Q[k,i]
// ---------------------------------------------------------------------------
__global__ __launch_bounds__(256, 3) void k_phase1(
    const float* __restrict__ obs2, const float* __restrict__ obs1,
    const float* __restrict__ bate_p, const float* __restrict__ ws,
    float* __restrict__ qs, int slen)
{
  const int w = threadIdx.x >> 6, lane = threadIdx.x & 63;
  const int b = blockIdx.x * 4 + w;
  const int j0 = (lane >> 3) * 4, i0 = (lane & 7) * 4;
  __shared__ __align__(16) float Q[4][32][36];
  __shared__ float cts[4][104];

  const int t0 = b * slen;
  {
    float bate = bate_p[0];
    for (int l = lane; l < slen; l += 64)
      cts[w][l] = obs2[t0 + l] - bate * obs1[t0 + l];
  }
  float4 Wr[32];
  const float* Wg = ws + OFF_W;
#pragma unroll
  for (int k = 0; k < 32; ++k) Wr[k] = *(const float4*)&Wg[k * 32 + j0];
  float4 i2vl = *(const float4*)&ws[OFF_I2V + j0];

#pragma unroll
  for (int m = 0; m < 4; ++m) {
    float4 v;
    v.x = (j0 + m == i0 + 0) ? 1.0f : 0.0f;
    v.y = (j0 + m == i0 + 1) ? 1.0f : 0.0f;
    v.z = (j0 + m == i0 + 2) ? 1.0f : 0.0f;
    v.w = (j0 + m == i0 + 3) ? 1.0f : 0.0f;
    *(float4*)&Q[w][j0 + m][i0] = v;
  }

  for (int s = 0; s < slen; ++s) {
    float ct = cts[w][s];
    float4 a0 = {0,0,0,0}, a1 = {0,0,0,0}, a2 = {0,0,0,0}, a3 = {0,0,0,0};
#pragma unroll
    for (int k = 0; k < 32; ++k) {
      float4 q = *(const float4*)&Q[w][k][i0];
      float4 wv = Wr[k];
      a0.x += wv.x * q.x; a0.y += wv.x * q.y; a0.z += wv.x * q.z; a0.w += wv.x * q.w;
      a1.x += wv.y * q.x; a1.y += wv.y * q.y; a1.z += wv.y * q.z; a1.w += wv.y * q.w;
      a2.x += wv.z * q.x; a2.y += wv.z * q.y; a2.z += wv.z * q.z; a2.w += wv.z * q.w;
      a3.x += wv.w * q.x; a3.y += wv.w * q.y; a3.z += wv.w * q.z; a3.w += wv.w * q.w;
    }
    float u0 = exp2f(-ct * i2vl.x), u1 = exp2f(-ct * i2vl.y);
    float u2 = exp2f(-ct * i2vl.z), u3 = exp2f(-ct * i2vl.w);
    a0.x *= u0; a0.y *= u0; a0.z *= u0; a0.w *= u0;
    a1.x *= u1; a1.y *= u1; a1.z *= u1; a1.w *= u1;
    a2.x *= u2; a2.y *= u2; a2.z *= u2; a2.w *= u2;
    a3.x *= u3; a3.y *= u3; a3.z *= u3; a3.w *= u3;
    if (((s & 7) == 7) || s == slen - 1) {   // scale-invariant rescale
      float ps = a0.x + a0.y + a0.z + a0.w + a1.x + a1.y + a1.z + a1.w
               + a2.x + a2.y + a2.z + a2.w + a3.x + a3.y + a3.z + a3.w;
#pragma unroll
      for (int o = 1; o < 64; o <<= 1) ps += __shfl_xor(ps, o);
      float g = __builtin_amdgcn_rcpf(ps);
      a0.x *= g; a0.y *= g; a0.z *= g; a0.w *= g;
      a1.x *= g; a1.y *= g; a1.z *= g; a1.w *= g;
      a2.x *= g; a2.y *= g; a2.z *= g; a2.w *= g;
      a3.x *= g; a3.y *= g; a3.z *= g; a3.w *= g;
    }
    *(float4*)&Q[w][j0 + 0][i0] = a0;
    *(float4*)&Q[w][j0 + 1][i0] = a1;
    *(float4*)&Q[w][j0 + 2][i0] = a2;
    *(float4*)&Q[w][j0 + 3][i0] = a3;
  }
  float* Qo = qs + (size_t)b * 1024;
#pragma unroll
  for (int m = 0; m < 4; ++m)
    *(float4*)&Qo[(j0 + m) * 32 + i0] = *(const float4*)&Q[w][j0 + m][i0];
}

// ---------------------------------------------------------------------------
// comb0: 4 waves/block, each wave builds one chunk product from f subchunk
// matrices. Private LDS slice, no barriers, single buffer.
// ---------------------------------------------------------------------------
__global__ __launch_bounds__(256, 3) void k_comb0(const float* __restrict__ qs,
                                                  float* __restrict__ qc, int f)
{
  const int w = threadIdx.x >> 6, lane = threadIdx.x & 63;
  const int b = blockIdx.x * 4 + w;
  const int j0 = (lane >> 3) * 4, i0 = (lane & 7) * 4;
  __shared__ __align__(16) float R[4][32][36];
  {
    const float* q0 = qs + (size_t)(b * f) * 1024;
#pragma unroll
    for (int m = 0; m < 4; ++m)
      *(float4*)&R[w][j0 + m][i0] = *(const float4*)&q0[(j0 + m) * 32 + i0];
  }
  for (int s = 1; s < f; ++s) {
    const float* ql = qs + (size_t)(b * f + s) * 1024;
    float Qv[4][32];
#pragma unroll
    for (int m = 0; m < 4; ++m)
#pragma unroll
      for (int kk = 0; kk < 8; ++kk) {
        float4 t = *(const float4*)&ql[(j0 + m) * 32 + kk * 4];
        Qv[m][kk * 4 + 0] = t.x; Qv[m][kk * 4 + 1] = t.y;
        Qv[m][kk * 4 + 2] = t.z; Qv[m][kk * 4 + 3] = t.w;
      }
    float4 a0 = {0,0,0,0}, a1 = {0,0,0,0}, a2 = {0,0,0,0}, a3 = {0,0,0,0};
#pragma unroll
    for (int k = 0; k < 32; ++k) {
      float4 r = *(const float4*)&R[w][k][i0];
      a0.x += Qv[0][k] * r.x; a0.y += Qv[0][k] * r.y; a0.z += Qv[0][k] * r.z; a0.w += Qv[0][k] * r.w;
      a1.x += Qv[1][k] * r.x; a1.y += Qv[1][k] * r.y; a1.z += Qv[1][k] * r.z; a1.w += Qv[1][k] * r.w;
      a2.x += Qv[2][k] * r.x; a2.y += Qv[2][k] * r.y; a2.z += Qv[2][k] * r.z; a2.w += Qv[2][k] * r.w;
      a3.x += Qv[3][k] * r.x; a3.y += Qv[3][k] * r.y; a3.z += Qv[3][k] * r.z; a3.w += Qv[3][k] * r.w;
    }
    if (s == f - 1) {
      float ps = a0.x + a0.y + a0.z + a0.w + a1.x + a1.y + a1.z + a1.w
               + a2.x + a2.y + a2.z + a2.w + a3.x + a3.y + a3.z + a3.w;
#pragma unroll
      for (int o = 1; o < 64; o <<= 1) ps += __shfl_xor(ps, o);
      float gg = __builtin_amdgcn_rcpf(ps);
      a0.x *= gg; a0.y *= gg; a0.z *= gg; a0.w *= gg;
      a1.x *= gg; a1.y *= gg; a1.z *= gg; a1.w *= gg;
      a2.x *= gg; a2.y *= gg; a2.z *= gg; a2.w *= gg;
      a3.x *= gg; a3.y *= gg; a3.z *= gg; a3.w *= gg;
    }
    *(float4*)&R[w][j0 + 0][i0] = a0;
    *(float4*)&R[w][j0 + 1][i0] = a1;
    *(float4*)&R[w][j0 + 2][i0] = a2;
    *(float4*)&R[w][j0 + 3][i0] = a3;
  }
  float* Ro = qc + (size_t)b * 1024;
#pragma unroll
  for (int m = 0; m < 4; ++m)
    *(float4*)&Ro[(j0 + m) * 32 + i0] = *(const float4*)&R[w][j0 + m][i0];
}

// ---------------------------------------------------------------------------
// comb1: 4 waves/block, each wave builds one group product from CGRP chunks.
// ---------------------------------------------------------------------------
__global__ __launch_bounds__(256, 3) void k_comb1(const float* __restrict__ qc,
                                                  float* __restrict__ r)
{
  const int w = threadIdx.x >> 6, lane = threadIdx.x & 63;
  const int g = blockIdx.x * 4 + w;
  const int j0 = (lane >> 3) * 4, i0 = (lane & 7) * 4;
  __shared__ __align__(16) float R[4][32][36];
  {
    const float* q0 = qc + (size_t)(g * CGRP) * 1024;
#pragma unroll
    for (int m = 0; m < 4; ++m)
      *(float4*)&R[w][j0 + m][i0] = *(const float4*)&q0[(j0 + m) * 32 + i0];
  }
  for (int c = 1; c < CGRP; ++c) {
    const float* ql = qc + (size_t)(g * CGRP + c) * 1024;
    float Qv[4][32];
#pragma unroll
    for (int m = 0; m < 4; ++m)
#pragma unroll
      for (int kk = 0; kk < 8; ++kk) {
        float4 t = *(const float4*)&ql[(j0 + m) * 32 + kk * 4];
        Qv[m][kk * 4 + 0] = t.x; Qv[m][kk * 4 + 1] = t.y;
        Qv[m][kk * 4 + 2] = t.z; Qv[m][kk * 4 + 3] = t.w;
      }
    float4 a0 = {0,0,0,0}, a1 = {0,0,0,0}, a2 = {0,0,0,0}, a3 = {0,0,0,0};
#pragma unroll
    for (int k = 0; k < 32; ++k) {
      float4 rr = *(const float4*)&R[w][k][i0];
      a0.x += Qv[0][k] * rr.x; a0.y += Qv[0][k] * rr.y; a0.z += Qv[0][k] * rr.z; a0.w += Qv[0][k] * rr.w;
      a1.x += Qv[1][k] * rr.x; a1.y += Qv[1][k] * rr.y; a1.z += Qv[1][k] * rr.z; a1.w += Qv[1][k] * rr.w;
      a2.x += Qv[2][k] * rr.x; a2.y += Qv[2][k] * rr.y; a2.z += Qv[2][k] * rr.z; a2.w += Qv[2][k] * rr.w;
      a3.x += Qv[3][k] * rr.x; a3.y += Qv[3][k] * rr.y; a3.z += Qv[3][k] * rr.z; a3.w += Qv[3][k] * rr.w;
    }
    if (((c & 3) == 3) || c == CGRP - 1) {
      float ps = a0.x + a0.y + a0.z + a0.w + a1.x + a1.y + a1.z + a1.w
               + a2.x + a2.y + a2.z + a2.w + a3.x + a3.y + a3.z + a3.w;
#pragma unroll
      for (int o = 1; o < 64; o <<= 1) ps += __shfl_xor(ps, o);
      float gg = __builtin_amdgcn_rcpf(ps);
      a0.x *= gg; a0.y *= gg; a0.z *= gg; a0.w *= gg;
      a1.x *= gg; a1.y *= gg; a1.z *= gg; a1.w *= gg;
      a2.x *= gg; a2.y *= gg; a2.z *= gg; a2.w *= gg;
      a3.x *= gg; a3.y *= gg; a3.z *= gg; a3.w *= gg;
    }
    *(float4*)&R[w][j0 + 0][i0] = a0;
    *(float4*)&R[w][j0 + 1][i0] = a1;
    *(float4*)&R[w][j0 + 2][i0] = a2;
    *(float4*)&R[w][j0 + 3][i0] = a3;
  }
  float* Ro = r + (size_t)g * 1024;
#pragma unroll
  for (int m = 0; m < 4; ++m)
    *(float4*)&Ro[(j0 + m) * 32 + i0] = *(const float4*)&R[w][j0 + m][i0];
}

// ---------------------------------------------------------------------------
// comb2: single wave scans GROUPS group matrices -> group-start states xg.
// ---------------------------------------------------------------------------
__global__ __launch_bounds__(64) void k_comb2(const float* __restrict__ pi,
                                              float* __restrict__ ws,
                                              const float* __restrict__ r)
{
  const int lane = threadIdx.x;
  const int j = lane & 31, h = lane >> 5;
  float x = pi[j];
  float4 c0, c1, c2, c3;
  {
    const float4* rv = (const float4*)(r + j * 32 + h * 16);
    c0 = rv[0]; c1 = rv[1]; c2 = rv[2]; c3 = rv[3];
  }
  for (int g = 0; g < GROUPS; ++g) {
    float4 n0 = {0,0,0,0}, n1 = {0,0,0,0}, n2 = {0,0,0,0}, n3 = {0,0,0,0};
    if (g + 1 < GROUPS) {
      const float4* rv = (const float4*)(r + (size_t)(g + 1) * 1024 + j * 32 + h * 16);
      n0 = rv[0]; n1 = rv[1]; n2 = rv[2]; n3 = rv[3];
    }
    if (lane < 32) ws[OFF_XG + g * 32 + j] = x;
    float y = 0.f;
    y += c0.x * __shfl(x, h * 16 + 0);  y += c0.y * __shfl(x, h * 16 + 1);
    y += c0.z * __shfl(x, h * 16 + 2);  y += c0.w * __shfl(x, h * 16 + 3);
    y += c1.x * __shfl(x, h * 16 + 4);  y += c1.y * __shfl(x, h * 16 + 5);
    y += c1.z * __shfl(x, h * 16 + 6);  y += c1.w * __shfl(x, h * 16 + 7);
    y += c2.x * __shfl(x, h * 16 + 8);  y += c2.y * __shfl(x, h * 16 + 9);
    y += c2.z * __shfl(x, h * 16 + 10); y += c2.w * __shfl(x, h * 16 + 11);
    y += c3.x * __shfl(x, h * 16 + 12); y += c3.y * __shfl(x, h * 16 + 13);
    y += c3.z * __shfl(x, h * 16 + 14); y += c3.w * __shfl(x, h * 16 + 15);
    y += __shfl_xor(y, 32);
    float s = y;
#pragma unroll
    for (int o = 1; o < 32; o <<= 1) s += __shfl_xor(s, o);
    x = y * __builtin_amdgcn_rcpf(s);
    c0 = n0; c1 = n1; c2 = n2; c3 = n3;
  }
}

// ---------------------------------------------------------------------------
// comb3: 4 waves/block, each wave scans one group's subchunk matrices -> e0
// ---------------------------------------------------------------------------
__global__ __launch_bounds__(256) void k_comb3(const float* __restrict__ ws,
                                               const float* __restrict__ qs,
                                               float* __restrict__ e0, int f)
{
  const int w = threadIdx.x >> 6, lane = threadIdx.x & 63;
  const int g = blockIdx.x * 4 + w;
  const int j = lane & 31, h = lane >> 5;
  const int nsub = CGRP * f;
  const size_t base = (size_t)g * nsub;
  float x = ws[OFF_XG + g * 32 + j];
  float4 c0, c1, c2, c3;
  {
    const float4* qv = (const float4*)(qs + base * 1024 + j * 32 + h * 16);
    c0 = qv[0]; c1 = qv[1]; c2 = qv[2]; c3 = qv[3];
  }
  for (int c = 0; c < nsub; ++c) {
    float4 n0 = {0,0,0,0}, n1 = {0,0,0,0}, n2 = {0,0,0,0}, n3 = {0,0,0,0};
    if (c + 1 < nsub) {
      const float4* qv = (const float4*)(qs + (base + c + 1) * 1024 + j * 32 + h * 16);
      n0 = qv[0]; n1 = qv[1]; n2 = qv[2]; n3 = qv[3];
    }
    if (lane < 32) e0[(base + c) * 32 + j] = x;
    float y = 0.f;
    y += c0.x * __shfl(x, h * 16 + 0);  y += c0.y * __shfl(x, h * 16 + 1);
    y += c0.z * __shfl(x, h * 16 + 2);  y += c0.w * __shfl(x, h * 16 + 3);
    y += c1.x * __shfl(x, h * 16 + 4);  y += c1.y * __shfl(x, h * 16 + 5);
    y += c1.z * __shfl(x, h * 16 + 6);  y += c1.w * __shfl(x, h * 16 + 7);
    y += c2.x * __shfl(x, h * 16 + 8);  y += c2.y * __shfl(x, h * 16 + 9);
    y += c2.z * __shfl(x, h * 16 + 10); y += c2.w * __shfl(x, h * 16 + 11);
    y += c3.x * __shfl(x, h * 16 + 12); y += c3.y * __shfl(x, h * 16 + 13);
    y += c3.z * __shfl(x, h * 16 + 14); y += c3.w * __shfl(x, h * 16 + 15);
    y += __shfl_xor(y, 32);
    float s = y;
#pragma unroll
    for (int o = 1; o < 32; o <<= 1) s += __shfl_xor(s, o);
    x = y * __builtin_amdgcn_rcpf(s);
    c0 = n0; c1 = n1; c2 = n2; c3 = n3;
  }
}

// ---------------------------------------------------------------------------
// Phase 2: 4 waves/block, each wave replays one subchunk (private LDS x,
// no barriers). Half 0: u.W^T x; half 1: u^2.W2^T x. loss_t = N2/S.
// ---------------------------------------------------------------------------
__global__ __launch_bounds__(256, 4) void k_phase2(
    const float* __restrict__ obs2, const float* __restrict__ obs1,
    const float* __restrict__ bate_p, const float* __restrict__ ws,
    const float* __restrict__ e0, float* __restrict__ lossbuf, int slen)
{
  const int w = threadIdx.x >> 6, lane = threadIdx.x & 63;
  const int b = blockIdx.x * 4 + w;
  const int j = lane & 31, h = lane >> 5;
  __shared__ float cts[4][104];
  __shared__ __align__(16) float xs[4][32];
  const int t0 = b * slen;
  {
    float bate = bate_p[0];
    for (int l = lane; l < slen; l += 64)
      cts[w][l] = obs2[t0 + l] - bate * obs1[t0 + l];
  }
  float Wc[32];
  const float* Wsel = ws + (h ? OFF_W2 : OFF_W);
#pragma unroll
  for (int k = 0; k < 32; ++k) Wc[k] = Wsel[k * 32 + j];
  const float i2vl = ws[OFF_I2V + j];
  if (lane < 32) xs[w][j] = e0[(size_t)b * 32 + j];

  float lossacc = 0.f;
  for (int s = 0; s < slen; ++s) {
    float ct = cts[w][s];
    float u  = exp2f(-ct * i2vl);
    float xk[32];
    const float4* xv = (const float4*)xs[w];
#pragma unroll
    for (int k8 = 0; k8 < 8; ++k8) {
      float4 q = xv[k8];
      xk[k8 * 4 + 0] = q.x; xk[k8 * 4 + 1] = q.y;
      xk[k8 * 4 + 2] = q.z; xk[k8 * 4 + 3] = q.w;
    }
    float dot = 0.f;
#pragma unroll
    for (int k = 0; k < 32; ++k) dot += Wc[k] * xk[k];
    float numj = u * dot;                 // meaningful on half 0
    float red  = h ? (u * u * dot) : numj;
#pragma unroll
    for (int o = 1; o < 32; o <<= 1) red += __shfl_xor(red, o);
    float cross = __shfl_xor(red, 32);
    float S  = h ? cross : red;
    float N2 = h ? red   : cross;
    float rs = __builtin_amdgcn_rcpf(S);
    lossacc += N2 * rs;
    if (lane < 32) xs[w][j] = numj * rs;
  }
  if (lane == 0) atomicAdd(&lossbuf[b & 63], lossacc);
}

__global__ __launch_bounds__(64) void k_finish(const float* __restrict__ lossbuf,
                                               float* __restrict__ out)
{
  float v = lossbuf[threadIdx.x];
#pragma unroll
  for (int o = 1; o < 64; o <<= 1) v += __shfl_xor(v, o);
  if (threadIdx.x == 0) out[0] = v;
}

extern "C" void kernel_launch(void* const* d_in, const int* in_sizes, int n_in,
                              void* d_out, int out_size, void* d_ws, size_t ws_size,
                              hipStream_t stream)
{
  (void)in_sizes; (void)n_in;
  const float* obs2 = (const float*)d_in[0];
  const float* obs1 = (const float*)d_in[1];
  const float* mean = (const float*)d_in[2];
  const float* var  = (const float*)d_in[3];
  const float* bate = (const float*)d_in[4];
  const float* pi   = (const float*)d_in[5];
  const float* aij  = (const float*)d_in[6];
  float* ws  = (float*)d_ws;
  float* out = (float*)d_out;

  // pick subchunk factor F by available workspace (constant across calls)
  size_t wsf = ws_size / sizeof(float);
  auto need = [](int F) -> size_t {
    return OFF_QS + (size_t)F * CHUNKS * 1024 + (F > 1 ? (size_t)CHUNKS * 1024 : 0)
         + (size_t)GROUPS * 1024 + (size_t)F * CHUNKS * 32;
  };
  int F = (wsf >= need(4)) ? 4 : (wsf >= need(2)) ? 2 : 1;
  const int SUB = CHUNKS * F, slen = TN / SUB;

  float* qs = ws + OFF_QS;
  float* qc = (F > 1) ? qs + (size_t)SUB * 1024 : qs;
  float* r  = qc + (size_t)CHUNKS * 1024;
  float* e0 = r  + (size_t)GROUPS * 1024;
  float* lb = ws + OFF_LB;

  hipMemsetAsync(out, 0, sizeof(float) * out_size, stream);
  hipMemsetAsync((void*)lb, 0, 64 * sizeof(float), stream);
  k_prep  <<<1,        256, 0, stream>>>(mean, var, bate, aij, ws);
  k_phase1<<<SUB / 4,  256, 0, stream>>>(obs2, obs1, bate, ws, qs, slen);
  if (F > 1)
    k_comb0<<<CHUNKS/4, 256, 0, stream>>>(qs, qc, F);
  k_comb1 <<<GROUPS/4, 256, 0, stream>>>(qc, r);
  k_comb2 <<<1,         64, 0, stream>>>(pi, ws, r);
  k_comb3 <<<GROUPS/4, 256, 0, stream>>>(ws, qs, e0, F);
  k_phase2<<<SUB / 4,  256, 0, stream>>>(obs2, obs1, bate, ws, e0, lb, slen);
  k_finish<<<1,         64, 0, stream>>>(lb, out);
}

// Round 5
// 258.493 us; speedup vs baseline: 3.3872x; 3.3872x over previous
//
#include <hip/hip_runtime.h>

constexpr int TN   = 100000;
constexpr int NCH  = 1250;
constexpr int CLEN = 80;            // NCH*CLEN == TN
constexpr int WARM = 512;           // warm-up steps (contraction forgets init)
constexpr int WPB  = 4;             // waves per block
constexpr int NBLK = (NCH + WPB - 1) / WPB;
constexpr int MAXS = WARM + CLEN;   // 592

constexpr float LOG2E = 1.4426950408889634f;

// float offsets into ws
constexpr size_t OFF_W   = 0;      // 32x32  W[i][j]  = aij*A_j*B_ij
constexpr size_t OFF_W2  = 1024;   // 32x32  W2[i][j] = W*A_j*B_ij
constexpr size_t OFF_I2V = 2048;   // 32     i2v_j * LOG2E
constexpr size_t OFF_LB  = 2112;   // 64     loss buckets

// ---------------------------------------------------------------------------
// Prep (1 block): W, W2, i2v*LOG2E
// ---------------------------------------------------------------------------
__global__ __launch_bounds__(256) void k_prep(
    const float* __restrict__ mean, const float* __restrict__ var,
    const float* __restrict__ bate_p, const float* __restrict__ aij,
    float* __restrict__ ws)
{
  const int tid = threadIdx.x;
  const int j = tid & 31, ig = tid >> 5;
  float vj   = var[j];
  float i2v  = 0.5f / vj;
  float norm = rsqrtf(2.0f * 3.1415926f * vj);
  float Aj   = norm * expf(mean[j] * i2v);
  float bate = bate_p[0];
  if (tid < 32) ws[OFF_I2V + tid] = i2v * LOG2E;
#pragma unroll
  for (int m = 0; m < 4; ++m) {
    int i = ig * 4 + m;
    float Bij = expf(-bate * mean[i] * i2v);
    float w = aij[i * 32 + j] * Aj * Bij;
    ws[OFF_W  + i * 32 + j] = w;
    ws[OFF_W2 + i * 32 + j] = w * Aj * Bij;
  }
}

// ---------------------------------------------------------------------------
// Main: one wave per chunk of CLEN steps, warm-started WARM steps early from
// a uniform state (Birkhoff contraction erases the init; chunks with
// t0 <= WARM start exactly from pi at t=0 -> exact). x lives in registers,
// broadcast via v_readlane (SGPR operand -> zero DS pressure). Lane half 0
// computes u.(W^T x); half 1 computes u^2.(W2^T x). No barriers.
//   step:  y_j = u_j (W^T x)_j ; S = sum y ; N2 = sum u_j^2 (W2^T x)_j
//          loss += N2/S ; x = y/S
// ---------------------------------------------------------------------------
__global__ __launch_bounds__(256) void k_main(
    const float* __restrict__ obs2, const float* __restrict__ obs1,
    const float* __restrict__ bate_p, const float* __restrict__ pi,
    const float* __restrict__ ws, float* __restrict__ lossbuf)
{
  const int w = threadIdx.x >> 6, lane = threadIdx.x & 63;
  const int wv = blockIdx.x * WPB + w;
  if (wv >= NCH) return;
  const int j = lane & 31, h = lane >> 5;
  __shared__ float cts[WPB][MAXS + 8];

  const int t0 = wv * CLEN;
  const int tw = (t0 > WARM) ? (t0 - WARM) : 0;
  const int n  = t0 + CLEN - tw;
  const int warmsteps = t0 - tw;
  {
    float bate = bate_p[0];
    for (int l = lane; l < n; l += 64)
      cts[w][l] = obs2[tw + l] - bate * obs1[tw + l];
  }
  float Wc[32];
  const float* Wsel = ws + (h ? OFF_W2 : OFF_W);
#pragma unroll
  for (int k = 0; k < 32; ++k) Wc[k] = Wsel[k * 32 + j];
  const float i2vl = ws[OFF_I2V + j];

  // start state: exact pi if warm-up reaches t=0, else uniform
  float x = (tw == 0) ? pi[j] : 0.03125f;

#define DOT_X(dot)                                                            \
  float dot;                                                                  \
  {                                                                           \
    float d0 = 0.f, d1 = 0.f, d2 = 0.f, d3 = 0.f;                             \
    _Pragma("unroll")                                                         \
    for (int k = 0; k < 32; k += 4) {                                         \
      d0 += Wc[k+0] * __int_as_float(__builtin_amdgcn_readlane(__float_as_int(x), k+0)); \
      d1 += Wc[k+1] * __int_as_float(__builtin_amdgcn_readlane(__float_as_int(x), k+1)); \
      d2 += Wc[k+2] * __int_as_float(__builtin_amdgcn_readlane(__float_as_int(x), k+2)); \
      d3 += Wc[k+3] * __int_as_float(__builtin_amdgcn_readlane(__float_as_int(x), k+3)); \
    }                                                                         \
    dot = (d0 + d1) + (d2 + d3);                                              \
  }

  int s = 0;
  // ---- warm-up: no loss, normalize every 4 steps (overflow-safe) ----
  for (; s < warmsteps; ++s) {
    float ct = cts[w][s];
    float u  = exp2f(-ct * i2vl);
    DOT_X(dot)
    x = u * dot;                     // meaningful on half 0 (readlane k<32)
    if ((s & 3) == 3) {
      float ssum = x;
#pragma unroll
      for (int o = 1; o < 32; o <<= 1) ssum += __shfl_xor(ssum, o);
      x *= __builtin_amdgcn_rcpf(ssum);
    }
  }
  // ---- owned range: accumulate loss, normalize every step ----
  float lossacc = 0.f;
  for (; s < n; ++s) {
    float ct = cts[w][s];
    float u  = exp2f(-ct * i2vl);
    DOT_X(dot)
    float val = (h ? (u * u) : u) * dot;
    float red = val;
#pragma unroll
    for (int o = 1; o < 32; o <<= 1) red += __shfl_xor(red, o);
    float cross = __shfl_xor(red, 32);
    float S  = h ? cross : red;
    float N2 = h ? red   : cross;
    float rs = __builtin_amdgcn_rcpf(S);
    lossacc += N2 * rs;
    x = (u * dot) * rs;
  }
  if (lane == 0) atomicAdd(&lossbuf[wv & 63], lossacc);
#undef DOT_X
}

__global__ __launch_bounds__(64) void k_finish(const float* __restrict__ lossbuf,
                                               float* __restrict__ out)
{
  float v = lossbuf[threadIdx.x];
#pragma unroll
  for (int o = 1; o < 64; o <<= 1) v += __shfl_xor(v, o);
  if (threadIdx.x == 0) out[0] = v;
}

extern "C" void kernel_launch(void* const* d_in, const int* in_sizes, int n_in,
                              void* d_out, int out_size, void* d_ws, size_t ws_size,
                              hipStream_t stream)
{
  (void)in_sizes; (void)n_in; (void)ws_size; (void)out_size;
  const float* obs2 = (const float*)d_in[0];
  const float* obs1 = (const float*)d_in[1];
  const float* mean = (const float*)d_in[2];
  const float* var  = (const float*)d_in[3];
  const float* bate = (const float*)d_in[4];
  const float* pi   = (const float*)d_in[5];
  const float* aij  = (const float*)d_in[6];
  float* ws  = (float*)d_ws;
  float* out = (float*)d_out;
  float* lb  = ws + OFF_LB;

  hipMemsetAsync((void*)lb, 0, 64 * sizeof(float), stream);
  k_prep  <<<1,    256, 0, stream>>>(mean, var, bate, aij, ws);
  k_main  <<<NBLK, 256, 0, stream>>>(obs2, obs1, bate, pi, ws, lb);
  k_finish<<<1,     64, 0, stream>>>(lb, out);
}

// Round 6
// 186.120 us; speedup vs baseline: 4.7044x; 1.3889x over previous
//
#include <hip/hip_runtime.h>

constexpr int TN   = 100000;
constexpr int NCH  = 2500;
constexpr int CLEN = 40;            // NCH*CLEN == TN
constexpr int WARM = 256;           // warm-up steps (contraction forgets init)
constexpr int WPB  = 4;             // waves per block
constexpr int NBLK = NCH / WPB;     // 625
constexpr int MAXS = WARM + CLEN;   // 296

constexpr float LOG2E = 1.4426950408889634f;

// float offsets into ws
constexpr size_t OFF_W    = 0;      // 32x32  W[i][j]  = aij*A_j*B_ij
constexpr size_t OFF_W2   = 1024;   // 32x32  W2[i][j] = W*A_j*B_ij
constexpr size_t OFF_I2V  = 2048;   // 32     i2v_j * LOG2E        (true, loss loop)
constexpr size_t OFF_I2VC = 2080;   // 32     (i2v_j - mean)*LOG2E (centered, warm loop)
constexpr size_t OFF_LB   = 2176;   // 64     loss buckets

// ---------------------------------------------------------------------------
// Prep (1 block): W, W2, i2v*LOG2E, centered i2v
// ---------------------------------------------------------------------------
__global__ __launch_bounds__(256) void k_prep(
    const float* __restrict__ mean, const float* __restrict__ var,
    const float* __restrict__ bate_p, const float* __restrict__ aij,
    float* __restrict__ ws)
{
  const int tid = threadIdx.x;
  const int j = tid & 31, ig = tid >> 5;
  float vj   = var[j];
  float i2v  = 0.5f / vj;
  float norm = rsqrtf(2.0f * 3.1415926f * vj);
  float Aj   = norm * expf(mean[j] * i2v);
  float bate = bate_p[0];
  if (tid < 32) {
    ws[OFF_I2V + tid] = i2v * LOG2E;
    // mean of i2v over the 32 lanes (offsets <=16 stay within lanes 0-31)
    float s = i2v;
#pragma unroll
    for (int o = 1; o < 32; o <<= 1) s += __shfl_xor(s, o);
    ws[OFF_I2VC + tid] = (i2v - s * 0.03125f) * LOG2E;
  }
#pragma unroll
  for (int m = 0; m < 4; ++m) {
    int i = ig * 4 + m;
    float Bij = expf(-bate * mean[i] * i2v);
    float w = aij[i * 32 + j] * Aj * Bij;
    ws[OFF_W  + i * 32 + j] = w;
    ws[OFF_W2 + i * 32 + j] = w * Aj * Bij;
  }
}

// ---------------------------------------------------------------------------
// Main: one wave per chunk of CLEN steps, warm-started WARM steps early from
// a uniform state (Birkhoff contraction erases the init; chunks with
// t0 <= WARM start exactly from pi at t=0 -> exact). x in registers,
// broadcast via v_readlane. Half 0: u.(W^T x); half 1: u^2.(W2^T x).
// Warm-up uses CENTERED u (uniform scalar factor per step is scale-invariant)
// so magnitudes stay bounded; rescale by 1/x_0 every 4 steps (3 VALU instrs,
// no cross-lane reduction). Loss loop uses true u and per-step 1/S normalize.
// ---------------------------------------------------------------------------
__global__ __launch_bounds__(256) void k_main(
    const float* __restrict__ obs2, const float* __restrict__ obs1,
    const float* __restrict__ bate_p, const float* __restrict__ pi,
    const float* __restrict__ ws, float* __restrict__ lossbuf)
{
  const int w = threadIdx.x >> 6, lane = threadIdx.x & 63;
  const int wv = blockIdx.x * WPB + w;
  const int j = lane & 31, h = lane >> 5;
  __shared__ float cts[WPB][MAXS + 8];

  const int t0 = wv * CLEN;
  const int tw = (t0 > WARM) ? (t0 - WARM) : 0;
  const int n  = t0 + CLEN - tw;
  const int warmsteps = t0 - tw;
  {
    float bate = bate_p[0];
    for (int l = lane; l < n; l += 64)
      cts[w][l] = obs2[tw + l] - bate * obs1[tw + l];
  }
  float Wc[32];
  const float* Wsel = ws + (h ? OFF_W2 : OFF_W);
#pragma unroll
  for (int k = 0; k < 32; ++k) Wc[k] = Wsel[k * 32 + j];
  const float i2vl  = ws[OFF_I2V  + j];
  const float i2vcl = ws[OFF_I2VC + j];

  // start state: exact pi if warm-up reaches t=0, else uniform
  float x = (tw == 0) ? pi[j] : 0.03125f;

  // 8-accumulator dot: 4-deep FMA chains + 3-level tree
#define DOT_X(dot)                                                            \
  float dot;                                                                  \
  {                                                                           \
    float d0=0.f,d1=0.f,d2=0.f,d3=0.f,d4=0.f,d5=0.f,d6=0.f,d7=0.f;            \
    _Pragma("unroll")                                                         \
    for (int k = 0; k < 32; k += 8) {                                         \
      d0 += Wc[k+0] * __int_as_float(__builtin_amdgcn_readlane(__float_as_int(x), k+0)); \
      d1 += Wc[k+1] * __int_as_float(__builtin_amdgcn_readlane(__float_as_int(x), k+1)); \
      d2 += Wc[k+2] * __int_as_float(__builtin_amdgcn_readlane(__float_as_int(x), k+2)); \
      d3 += Wc[k+3] * __int_as_float(__builtin_amdgcn_readlane(__float_as_int(x), k+3)); \
      d4 += Wc[k+4] * __int_as_float(__builtin_amdgcn_readlane(__float_as_int(x), k+4)); \
      d5 += Wc[k+5] * __int_as_float(__builtin_amdgcn_readlane(__float_as_int(x), k+5)); \
      d6 += Wc[k+6] * __int_as_float(__builtin_amdgcn_readlane(__float_as_int(x), k+6)); \
      d7 += Wc[k+7] * __int_as_float(__builtin_amdgcn_readlane(__float_as_int(x), k+7)); \
    }                                                                         \
    dot = ((d0 + d1) + (d2 + d3)) + ((d4 + d5) + (d6 + d7));                  \
  }

  int s = 0;
  // ---- warm-up: centered u, no cross-lane reduction in the chain ----
  for (; s < warmsteps; ++s) {
    float ct = cts[w][s];
    float u  = exp2f(-ct * i2vcl);
    DOT_X(dot)
    x = u * dot;                      // meaningful on half 0 (readlane k<32)
    if ((s & 3) == 3)
      x *= __builtin_amdgcn_rcpf(
             __int_as_float(__builtin_amdgcn_readlane(__float_as_int(x), 0)));
  }
  // ---- owned range: true u, accumulate loss, normalize every step ----
  float lossacc = 0.f;
  for (; s < n; ++s) {
    float ct = cts[w][s];
    float u  = exp2f(-ct * i2vl);
    DOT_X(dot)
    float val = (h ? (u * u) : u) * dot;
    float red = val;
#pragma unroll
    for (int o = 1; o < 32; o <<= 1) red += __shfl_xor(red, o);
    float cross = __shfl_xor(red, 32);
    float S  = h ? cross : red;
    float N2 = h ? red   : cross;
    float rs = __builtin_amdgcn_rcpf(S);
    lossacc += N2 * rs;
    x = (u * dot) * rs;
  }
  if (lane == 0) atomicAdd(&lossbuf[wv & 63], lossacc);
#undef DOT_X
}

__global__ __launch_bounds__(64) void k_finish(const float* __restrict__ lossbuf,
                                               float* __restrict__ out)
{
  float v = lossbuf[threadIdx.x];
#pragma unroll
  for (int o = 1; o < 64; o <<= 1) v += __shfl_xor(v, o);
  if (threadIdx.x == 0) out[0] = v;
}

extern "C" void kernel_launch(void* const* d_in, const int* in_sizes, int n_in,
                              void* d_out, int out_size, void* d_ws, size_t ws_size,
                              hipStream_t stream)
{
  (void)in_sizes; (void)n_in; (void)ws_size; (void)out_size;
  const float* obs2 = (const float*)d_in[0];
  const float* obs1 = (const float*)d_in[1];
  const float* mean = (const float*)d_in[2];
  const float* var  = (const float*)d_in[3];
  const float* bate = (const float*)d_in[4];
  const float* pi   = (const float*)d_in[5];
  const float* aij  = (const float*)d_in[6];
  float* ws  = (float*)d_ws;
  float* out = (float*)d_out;
  float* lb  = ws + OFF_LB;

  hipMemsetAsync((void*)lb, 0, 64 * sizeof(float), stream);
  k_prep  <<<1,    256, 0, stream>>>(mean, var, bate, aij, ws);
  k_main  <<<NBLK, 256, 0, stream>>>(obs2, obs1, bate, pi, ws, lb);
  k_finish<<<1,     64, 0, stream>>>(lb, out);
}

// Round 7
// 136.467 us; speedup vs baseline: 6.4160x; 1.3638x over previous
//
#include <hip/hip_runtime.h>

constexpr int TN   = 100000;
constexpr int NCH  = 2500;
constexpr int CLEN = 40;            // NCH*CLEN == TN
constexpr int WARM = 128;           // warm-up steps (contraction forgets init)
constexpr int WPB  = 4;             // waves per block
constexpr int NBLK = NCH / WPB;     // 625
constexpr int MAXS = WARM + CLEN;   // 168

constexpr float LOG2E = 1.4426950408889634f;
constexpr float PI_F  = 3.1415926f;

// ---------------------------------------------------------------------------
// Main kernel: fused prep + warm-up + loss.
// One wave per chunk of CLEN steps, warm-started WARM steps early from a
// uniform state (Birkhoff contraction erases the init; chunks with
// t0 <= WARM start exactly from pi at t=0 -> exact).
// State transpose per step goes through wave-private LDS (1 ds_write_b32 +
// 8 broadcast ds_read_b128), not readlanes. Wave lockstep + in-order DS
// pipeline => no barriers in the loop. Warm-up runs on CENTERED u (any
// uniform per-step scalar is scale-invariant) with unnormalized state and a
// cheap every-4-step rescale by 1/y_0. Loss loop uses true u:
//   a_j = u_j (W^T y)_j ; b_j = u_j^2 (W2^T y)_j ; loss_t = (sum b)/(sum a)
// (y scale cancels in the ratio; y normalized by 1/sum(a) per step.)
// ---------------------------------------------------------------------------
__global__ __launch_bounds__(256) void k_main(
    const float* __restrict__ obs2, const float* __restrict__ obs1,
    const float* __restrict__ mean_p, const float* __restrict__ var_p,
    const float* __restrict__ bate_p, const float* __restrict__ pi_p,
    const float* __restrict__ aij, float* __restrict__ lossbuf)
{
  const int w = threadIdx.x >> 6, lane = threadIdx.x & 63;
  const int wv = blockIdx.x * WPB + w;
  const int j = lane & 31, h = lane >> 5;

  __shared__ __align__(16) float Wsh[2][32][32];   // [sel][k][j]
  __shared__ __align__(16) float ybuf[WPB][64];    // [wave][lane] (y in 0..31)
  __shared__ float cts[WPB][MAXS + 8];

  // --- block-cooperative prep of W, W2 into LDS (once) ---
  {
    const int tid = threadIdx.x;
    const int jj = tid & 31, ig = tid >> 5;
    float vj   = var_p[jj];
    float i2v  = 0.5f / vj;
    float norm = rsqrtf(2.0f * PI_F * vj);
    float Aj   = norm * expf(mean_p[jj] * i2v);
    float bate = bate_p[0];
#pragma unroll
    for (int m = 0; m < 4; ++m) {
      int i = ig * 4 + m;
      float Bij = expf(-bate * mean_p[i] * i2v);
      float wq = aij[i * 32 + jj] * Aj * Bij;
      Wsh[0][i][jj] = wq;
      Wsh[1][i][jj] = wq * Aj * Bij;
    }
  }

  // --- per-lane constants ---
  float vj  = var_p[j];
  float i2v = 0.5f / vj;
  float i2vsum = i2v;
#pragma unroll
  for (int o = 1; o < 32; o <<= 1) i2vsum += __shfl_xor(i2vsum, o);
  const float i2vl  = i2v * LOG2E;                       // true (loss loop)
  const float i2vcl = (i2v - i2vsum * 0.03125f) * LOG2E; // centered (warm loop)

  // --- stage cts for this wave's range ---
  const int t0 = wv * CLEN;
  const int tw = (t0 > WARM) ? (t0 - WARM) : 0;
  const int n  = t0 + CLEN - tw;
  const int warmsteps = t0 - tw;
  {
    float bate = bate_p[0];
    for (int l = lane; l < n; l += 64)
      cts[w][l] = obs2[tw + l] - bate * obs1[tw + l];
  }
  __syncthreads();   // Wsh ready (only barrier in the kernel)

  // --- W columns into registers ---
  float Wc[32];
#pragma unroll
  for (int k = 0; k < 32; ++k) Wc[k] = Wsh[h][k][j];

  // start state: exact pi if warm-up reaches t=0, else uniform
  ybuf[w][lane] = (tw == 0) ? pi_p[j] : 0.03125f;

  // broadcast-load y (8 x ds_read_b128, uniform address) + 8-acc dot
#define DOT_Y(dot)                                                            \
  float dot;                                                                  \
  {                                                                           \
    const float4* yv = (const float4*)ybuf[w];                                \
    float4 y0 = yv[0], y1 = yv[1], y2 = yv[2], y3 = yv[3];                    \
    float4 y4 = yv[4], y5 = yv[5], y6 = yv[6], y7 = yv[7];                    \
    float d0 = Wc[0]*y0.x + Wc[4]*y1.x;   float d1 = Wc[1]*y0.y + Wc[5]*y1.y; \
    float d2 = Wc[2]*y0.z + Wc[6]*y1.z;   float d3 = Wc[3]*y0.w + Wc[7]*y1.w; \
    float d4 = Wc[8]*y2.x + Wc[12]*y3.x;  float d5 = Wc[9]*y2.y + Wc[13]*y3.y;\
    float d6 = Wc[10]*y2.z + Wc[14]*y3.z; float d7 = Wc[11]*y2.w + Wc[15]*y3.w;\
    d0 += Wc[16]*y4.x; d1 += Wc[17]*y4.y; d2 += Wc[18]*y4.z; d3 += Wc[19]*y4.w;\
    d4 += Wc[20]*y5.x; d5 += Wc[21]*y5.y; d6 += Wc[22]*y5.z; d7 += Wc[23]*y5.w;\
    d0 += Wc[24]*y6.x; d1 += Wc[25]*y6.y; d2 += Wc[26]*y6.z; d3 += Wc[27]*y6.w;\
    d4 += Wc[28]*y7.x; d5 += Wc[29]*y7.y; d6 += Wc[30]*y7.z; d7 += Wc[31]*y7.w;\
    dot = ((d0 + d1) + (d2 + d3)) + ((d4 + d5) + (d6 + d7));                  \
  }

  int s = 0;
  // ---- warm-up: centered u, unnormalized y, cheap periodic rescale ----
  for (; s < warmsteps; ++s) {
    float ct = cts[w][s];
    float u  = exp2f(-ct * i2vcl);
    DOT_Y(dot)
    float a = u * dot;
    if ((s & 3) == 3)
      a *= __builtin_amdgcn_rcpf(__int_as_float(
             __builtin_amdgcn_readfirstlane(__float_as_int(a))));
    ybuf[w][lane] = a;   // after all reads (program order, in-order DS)
  }
  // ---- owned range: true u, accumulate loss, per-step normalize ----
  float lossacc = 0.f;
  for (; s < n; ++s) {
    float ct = cts[w][s];
    float u  = exp2f(-ct * i2vl);
    DOT_Y(dot)
    float val = (h ? (u * u) : u) * dot;
    float red = val;
#pragma unroll
    for (int o = 1; o < 32; o <<= 1) red += __shfl_xor(red, o);
    float cross = __shfl_xor(red, 32);
    float S  = h ? cross : red;
    float N2 = h ? red   : cross;
    float rs = __builtin_amdgcn_rcpf(S);
    lossacc += N2 * rs;
    ybuf[w][lane] = (u * dot) * rs;
  }
  if (lane == 0) lossbuf[wv] = lossacc;
#undef DOT_Y
}

// ---------------------------------------------------------------------------
// Finish: sum NCH per-chunk losses -> out[0]
// ---------------------------------------------------------------------------
__global__ __launch_bounds__(256) void k_finish(const float* __restrict__ lb,
                                                float* __restrict__ out)
{
  const int tid = threadIdx.x;
  float v = 0.f;
  for (int l = tid; l < NCH; l += 256) v += lb[l];
#pragma unroll
  for (int o = 1; o < 64; o <<= 1) v += __shfl_xor(v, o);
  __shared__ float part[4];
  if ((tid & 63) == 0) part[tid >> 6] = v;
  __syncthreads();
  if (tid == 0) out[0] = part[0] + part[1] + part[2] + part[3];
}

extern "C" void kernel_launch(void* const* d_in, const int* in_sizes, int n_in,
                              void* d_out, int out_size, void* d_ws, size_t ws_size,
                              hipStream_t stream)
{
  (void)in_sizes; (void)n_in; (void)ws_size; (void)out_size;
  const float* obs2 = (const float*)d_in[0];
  const float* obs1 = (const float*)d_in[1];
  const float* mean = (const float*)d_in[2];
  const float* var  = (const float*)d_in[3];
  const float* bate = (const float*)d_in[4];
  const float* pi   = (const float*)d_in[5];
  const float* aij  = (const float*)d_in[6];
  float* lb  = (float*)d_ws;           // NCH floats, every slot written
  float* out = (float*)d_out;

  k_main  <<<NBLK, 256, 0, stream>>>(obs2, obs1, mean, var, bate, pi, aij, lb);
  k_finish<<<1,    256, 0, stream>>>(lb, out);
}

// Round 8
// 109.884 us; speedup vs baseline: 7.9682x; 1.2419x over previous
//
#include <hip/hip_runtime.h>

constexpr int TN   = 100000;
constexpr int NCH  = 2000;
constexpr int CLEN = 50;            // NCH*CLEN == TN
constexpr int WARM = 64;            // warm-up steps (contraction forgets init)
constexpr int WPB  = 4;             // waves per block
constexpr int NBLK = NCH / WPB;     // 500
constexpr int MAXS = WARM + CLEN;   // 114

constexpr float LOG2E = 1.4426950408889634f;
constexpr float PI_F  = 3.1415926f;

// DPP row-rotate by N within 16-lane rows (direction auto-detected at runtime)
#define ROR(src, N) __int_as_float(__builtin_amdgcn_mov_dpp( \
    __float_as_int(src), 0x120 + (N), 0xF, 0xF, false))

#define ROTS(SRC, R)                                                          \
  float R##1 = ROR(SRC, 1),  R##2 = ROR(SRC, 2),  R##3 = ROR(SRC, 3),         \
        R##4 = ROR(SRC, 4),  R##5 = ROR(SRC, 5),  R##6 = ROR(SRC, 6),         \
        R##7 = ROR(SRC, 7),  R##8 = ROR(SRC, 8),  R##9 = ROR(SRC, 9),         \
        R##10 = ROR(SRC,10), R##11 = ROR(SRC,11), R##12 = ROR(SRC,12),        \
        R##13 = ROR(SRC,13), R##14 = ROR(SRC,14), R##15 = ROR(SRC,15);

#define DOT16(Wr, SRC, R, d0,d1,d2,d3,d4,d5,d6,d7)                            \
  d0 += Wr[0]*(SRC);  d1 += Wr[1]*R##1;   d2 += Wr[2]*R##2;   d3 += Wr[3]*R##3;   \
  d4 += Wr[4]*R##4;   d5 += Wr[5]*R##5;   d6 += Wr[6]*R##6;   d7 += Wr[7]*R##7;   \
  d0 += Wr[8]*R##8;   d1 += Wr[9]*R##9;   d2 += Wr[10]*R##10; d3 += Wr[11]*R##11; \
  d4 += Wr[12]*R##12; d5 += Wr[13]*R##13; d6 += Wr[14]*R##14; d7 += Wr[15]*R##15;

// ---------------------------------------------------------------------------
// k_main: fused prep + warm-up + loss. One wave per chunk of CLEN steps,
// warm-started WARM steps early (chunks with t0 <= WARM start exactly from pi
// at t=0). State y_j lives IN lane j (duplicated across the two 32-halves);
// the matvec dot_j = sum_k W[k,j] y_k is computed with 15 parallel DPP
// ROW_ROR rotations per 16-block (+ one shfl_xor(16) block swap), so the
// recursion chain is pure VALU — no LDS latency in the serial chain, no
// barriers. Warm-up: centered u (uniform per-step scalar is scale-invariant),
// W-dot only, cheap rescale by 1/y_0 every 4 steps. Loss: both W and W2 dots,
//   a_j = u_j (W^T y)_j ; b_j = u_j^2 (W2^T y)_j ; loss_t = (sum b)/(sum a)
// with y normalized by 1/sum(a) per step.
// ---------------------------------------------------------------------------
__global__ __launch_bounds__(256, 2) void k_main(
    const float* __restrict__ obs2, const float* __restrict__ obs1,
    const float* __restrict__ mean_p, const float* __restrict__ var_p,
    const float* __restrict__ bate_p, const float* __restrict__ pi_p,
    const float* __restrict__ aij, float* __restrict__ lossbuf)
{
  const int w = threadIdx.x >> 6, lane = threadIdx.x & 63;
  const int wv = blockIdx.x * WPB + w;
  const int i   = lane & 15;
  const int blk = (lane >> 4) & 1;
  const int j   = blk * 16 + i;        // this lane's state/output index
  const int ob  = blk * 16;            // own 16-block base (k index)
  const int nb  = 16 - ob;             // other block base

  __shared__ __align__(16) float Wsh[2][32][32];   // [sel][k][j]
  __shared__ float cts[WPB][MAXS + 2];

  // --- block-cooperative prep of W, W2 into LDS (once) ---
  {
    const int tid = threadIdx.x;
    const int jj = tid & 31, ig = tid >> 5;
    float vjq  = var_p[jj];
    float i2vq = 0.5f / vjq;
    float norm = rsqrtf(2.0f * PI_F * vjq);
    float Aj   = norm * expf(mean_p[jj] * i2vq);
    float bate = bate_p[0];
#pragma unroll
    for (int m = 0; m < 4; ++m) {
      int ii = ig * 4 + m;
      float Bij = expf(-bate * mean_p[ii] * i2vq);
      float wq = aij[ii * 32 + jj] * Aj * Bij;
      Wsh[0][ii][jj] = wq;
      Wsh[1][ii][jj] = wq * Aj * Bij;
    }
  }

  // --- per-lane exponent constants ---
  float vj  = var_p[j];
  float i2v = 0.5f / vj;
  float s_  = i2v;
#pragma unroll
  for (int o = 1; o < 32; o <<= 1) s_ += __shfl_xor(s_, o);
  const float i2vl = i2v * LOG2E;                      // true (loss)
  const float i2vc = (i2v - s_ * 0.03125f) * LOG2E;    // centered (warm)

  // --- stage cts for this wave's range ---
  const int t0 = wv * CLEN;
  const int tw = (t0 > WARM) ? (t0 - WARM) : 0;
  const int n  = t0 + CLEN - tw;
  const int warmsteps = t0 - tw;
  {
    float bate = bate_p[0];
    for (int l = lane; l < n; l += 64)
      cts[w][l] = obs2[tw + l] - bate * obs1[tw + l];
  }
  __syncthreads();   // Wsh ready (only barrier)

  // --- rotation direction probe (makes ROW_ROR direction irrelevant) ---
  int dird;
  { int p = __builtin_amdgcn_mov_dpp(i, 0x121, 0xF, 0xF, false);
    dird = (p - i) & 15; }

  // --- weights in rotation order: after N rotations this lane holds
  //     y[(i + N*dird)&15] of the block, so pair it with W[base+that, j] ---
  float WA[16], WB[16], VA[16], VB[16];
#pragma unroll
  for (int N = 0; N < 16; ++N) {
    int kk = (i + N * dird) & 15;
    WA[N] = Wsh[0][ob + kk][j];
    WB[N] = Wsh[0][nb + kk][j];
    VA[N] = Wsh[1][ob + kk][j];
    VB[N] = Wsh[1][nb + kk][j];
  }

  // start state: exact pi if warm-up reaches t=0, else uniform
  float y  = (tw == 0) ? pi_p[j] : 0.03125f;
  float y2 = __shfl_xor(y, 16);    // other block's components, same i

  int s = 0;
  // ---- warm-up: centered u, W-dot only ----
  for (; s < warmsteps; ++s) {
    float ct = cts[w][s];
    float u  = exp2f(-ct * i2vc);
    ROTS(y, a) ROTS(y2, b)
    float d0=0,d1=0,d2=0,d3=0,d4=0,d5=0,d6=0,d7=0;
    DOT16(WA, y,  a, d0,d1,d2,d3,d4,d5,d6,d7)
    DOT16(WB, y2, b, d0,d1,d2,d3,d4,d5,d6,d7)
    float dot = ((d0+d1)+(d2+d3)) + ((d4+d5)+(d6+d7));
    y = u * dot;
    if ((s & 3) == 3)
      y *= __builtin_amdgcn_rcpf(__int_as_float(
             __builtin_amdgcn_readfirstlane(__float_as_int(y))));
    y2 = __shfl_xor(y, 16);
  }
  // ---- owned range: both dots, loss, per-step normalize ----
  float lossacc = 0.f;
  const int h = lane >> 5;
  for (; s < n; ++s) {
    float ct = cts[w][s];
    float u  = exp2f(-ct * i2vl);
    ROTS(y, a) ROTS(y2, b)
    float d0=0,d1=0,d2=0,d3=0,d4=0,d5=0,d6=0,d7=0;
    float e0=0,e1=0,e2=0,e3=0,e4=0,e5=0,e6=0,e7=0;
    DOT16(WA, y,  a, d0,d1,d2,d3,d4,d5,d6,d7)
    DOT16(WB, y2, b, d0,d1,d2,d3,d4,d5,d6,d7)
    DOT16(VA, y,  a, e0,e1,e2,e3,e4,e5,e6,e7)
    DOT16(VB, y2, b, e0,e1,e2,e3,e4,e5,e6,e7)
    float dotW = ((d0+d1)+(d2+d3)) + ((d4+d5)+(d6+d7));
    float dotV = ((e0+e1)+(e2+e3)) + ((e4+e5)+(e6+e7));
    float numj = u * dotW;
    float n2j  = (u * u) * dotV;
    float red  = h ? n2j : numj;
#pragma unroll
    for (int o = 1; o < 32; o <<= 1) red += __shfl_xor(red, o);
    float cross = __shfl_xor(red, 32);
    float S  = h ? cross : red;
    float N2 = h ? red   : cross;
    float rs = __builtin_amdgcn_rcpf(S);
    lossacc += N2 * rs;
    y  = numj * rs;
    y2 = __shfl_xor(y, 16);
  }
  if (lane == 0) lossbuf[wv] = lossacc;
}

// ---------------------------------------------------------------------------
// Finish: sum NCH per-chunk losses -> out[0]
// ---------------------------------------------------------------------------
__global__ __launch_bounds__(256) void k_finish(const float* __restrict__ lb,
                                                float* __restrict__ out)
{
  const int tid = threadIdx.x;
  float v = 0.f;
  for (int l = tid; l < NCH; l += 256) v += lb[l];
#pragma unroll
  for (int o = 1; o < 64; o <<= 1) v += __shfl_xor(v, o);
  __shared__ float part[4];
  if ((tid & 63) == 0) part[tid >> 6] = v;
  __syncthreads();
  if (tid == 0) out[0] = part[0] + part[1] + part[2] + part[3];
}

extern "C" void kernel_launch(void* const* d_in, const int* in_sizes, int n_in,
                              void* d_out, int out_size, void* d_ws, size_t ws_size,
                              hipStream_t stream)
{
  (void)in_sizes; (void)n_in; (void)ws_size; (void)out_size;
  const float* obs2 = (const float*)d_in[0];
  const float* obs1 = (const float*)d_in[1];
  const float* mean = (const float*)d_in[2];
  const float* var  = (const float*)d_in[3];
  const float* bate = (const float*)d_in[4];
  const float* pi   = (const float*)d_in[5];
  const float* aij  = (const float*)d_in[6];
  float* lb  = (float*)d_ws;           // NCH floats, every slot written
  float* out = (float*)d_out;

  k_main  <<<NBLK, 256, 0, stream>>>(obs2, obs1, mean, var, bate, pi, aij, lb);
  k_finish<<<1,    256, 0, stream>>>(lb, out);
}

// Round 9
// 94.341 us; speedup vs baseline: 9.2809x; 1.1647x over previous
//
#include <hip/hip_runtime.h>

constexpr int TN   = 100000;
constexpr int NCH  = 2500;
constexpr int CLEN = 40;            // NCH*CLEN == TN
constexpr int WARM = 32;            // warm-up steps (contraction forgets init)
constexpr int WPB  = 4;             // waves per block
constexpr int NBLK = NCH / WPB;     // 625
constexpr int MAXS = WARM + CLEN;   // 72

constexpr float LOG2E = 1.4426950408889634f;
constexpr float PI_F  = 3.1415926f;

// DPP row-rotate by N within 16-lane rows (direction auto-detected at runtime)
#define ROR(src, N) __int_as_float(__builtin_amdgcn_mov_dpp( \
    __float_as_int(src), 0x120 + (N), 0xF, 0xF, false))

#define ROTS(SRC, R)                                                          \
  float R##1 = ROR(SRC, 1),  R##2 = ROR(SRC, 2),  R##3 = ROR(SRC, 3),         \
        R##4 = ROR(SRC, 4),  R##5 = ROR(SRC, 5),  R##6 = ROR(SRC, 6),         \
        R##7 = ROR(SRC, 7),  R##8 = ROR(SRC, 8),  R##9 = ROR(SRC, 9),         \
        R##10 = ROR(SRC,10), R##11 = ROR(SRC,11), R##12 = ROR(SRC,12),        \
        R##13 = ROR(SRC,13), R##14 = ROR(SRC,14), R##15 = ROR(SRC,15);

// 16-FMA partial dot against rotation-ordered weights (4 chains + tree)
#define DOT16(Wr, SRC, R, dd)                                                 \
  float dd;                                                                   \
  { float q0 = Wr[0]*(SRC)  + Wr[4]*R##4;                                     \
    float q1 = Wr[1]*R##1   + Wr[5]*R##5;                                     \
    float q2 = Wr[2]*R##2   + Wr[6]*R##6;                                     \
    float q3 = Wr[3]*R##3   + Wr[7]*R##7;                                     \
    q0 += Wr[8]*R##8;   q1 += Wr[9]*R##9;                                     \
    q2 += Wr[10]*R##10; q3 += Wr[11]*R##11;                                   \
    q0 += Wr[12]*R##12; q1 += Wr[13]*R##13;                                   \
    q2 += Wr[14]*R##14; q3 += Wr[15]*R##15;                                   \
    dd = (q0 + q1) + (q2 + q3); }

// 16-lane ring reduction via rotate-adds (direction-agnostic), stays on VALU
#define RING16(v) { v += ROR(v,1); v += ROR(v,2); v += ROR(v,4); v += ROR(v,8); }

// ---------------------------------------------------------------------------
// k_main: fused prep + warm-up + loss. One wave per chunk of CLEN steps,
// warm-started WARM steps early (chunks with t0 <= WARM start exactly from pi
// at t=0; Birkhoff contraction erases the uniform init otherwise).
// K-SPLIT layout: lane l covers k-block h = l>>5 for output j = l&31. Each
// step: 15 DPP rotations of the lane's half-state, 16 FMAs -> partial dot,
// one shfl_xor(32) combine. Loss steps add the W2 partial (16 FMAs, shared
// rotations) and reduce S = sum_j u_j dotW_j, N2 = sum_j u_j^2 dotW2_j with
// a DPP ring reduce. loss_t = N2/S; y normalized by 1/S per step.
// Warm-up uses CENTERED u (uniform per-step scalar is scale-invariant) and a
// cheap every-4-step rescale by 1/y_0. No barriers after the prep sync.
// ---------------------------------------------------------------------------
__global__ __launch_bounds__(256, 3) void k_main(
    const float* __restrict__ obs2, const float* __restrict__ obs1,
    const float* __restrict__ mean_p, const float* __restrict__ var_p,
    const float* __restrict__ bate_p, const float* __restrict__ pi_p,
    const float* __restrict__ aij, float* __restrict__ lossbuf)
{
  const int w = threadIdx.x >> 6, lane = threadIdx.x & 63;
  const int wv = blockIdx.x * WPB + w;
  const int i  = lane & 15;
  const int h  = lane >> 5;           // k-half this lane covers
  const int j  = lane & 31;           // this lane's output index
  const int kb = h * 16;              // k-block base

  __shared__ __align__(16) float Wsh[2][32][32];   // [sel][k][j]
  __shared__ float cts[WPB][MAXS + 2];

  // --- block-cooperative prep of W, W2 into LDS (once) ---
  {
    const int tid = threadIdx.x;
    const int jj = tid & 31, ig = tid >> 5;
    float vjq  = var_p[jj];
    float i2vq = 0.5f / vjq;
    float norm = rsqrtf(2.0f * PI_F * vjq);
    float Aj   = norm * expf(mean_p[jj] * i2vq);
    float bate = bate_p[0];
#pragma unroll
    for (int m = 0; m < 4; ++m) {
      int ii = ig * 4 + m;
      float Bij = expf(-bate * mean_p[ii] * i2vq);
      float wq = aij[ii * 32 + jj] * Aj * Bij;
      Wsh[0][ii][jj] = wq;
      Wsh[1][ii][jj] = wq * Aj * Bij;
    }
  }

  // --- per-lane exponent constants (j-indexed; halves duplicate) ---
  float vj  = var_p[j];
  float i2v = 0.5f / vj;
  float s_  = i2v;
#pragma unroll
  for (int o = 1; o < 32; o <<= 1) s_ += __shfl_xor(s_, o);
  const float i2vl = i2v * LOG2E;                      // true (loss)
  const float i2vc = (i2v - s_ * 0.03125f) * LOG2E;    // centered (warm)

  // --- stage cts for this wave's range ---
  const int t0 = wv * CLEN;
  const int tw = (t0 > WARM) ? (t0 - WARM) : 0;
  const int n  = t0 + CLEN - tw;
  const int warmsteps = t0 - tw;
  {
    float bate = bate_p[0];
    for (int l = lane; l < n; l += 64)
      cts[w][l] = obs2[tw + l] - bate * obs1[tw + l];
  }
  __syncthreads();   // Wsh ready (only barrier)

  // --- rotation direction probe (ROW_ROR direction made irrelevant) ---
  int dird;
  { int p = __builtin_amdgcn_mov_dpp(i, 0x121, 0xF, 0xF, false);
    dird = (p - i) & 15; }

  // --- rotation-ordered weights for this lane's k-block, output j ---
  float Wr[16], Vr[16];
#pragma unroll
  for (int N = 0; N < 16; ++N) {
    int kk = (i + N * dird) & 15;
    Wr[N] = Wsh[0][kb + kk][j];
    Vr[N] = Wsh[1][kb + kk][j];
  }

  // ysrc layout: lane must hold y_{kb + (l&15)}; from the j-indexed y this is
  // own y when (bit4 == h), else the xor-16 partner's value.
  const bool takeT = (((lane >> 4) & 1) ^ h) != 0;

  float y = (tw == 0) ? pi_p[j] : 0.03125f;
  float t = __shfl_xor(y, 16);
  float ysrc = takeT ? t : y;

  int s = 0;
  // ---- warm-up: centered u, W-dot only ----
  for (; s < warmsteps; ++s) {
    float ct = cts[w][s];
    float u  = exp2f(-ct * i2vc);
    ROTS(ysrc, a)
    DOT16(Wr, ysrc, a, pW)
    float dot = pW + __shfl_xor(pW, 32);
    y = u * dot;
    if ((s & 3) == 3)
      y *= __builtin_amdgcn_rcpf(__int_as_float(
             __builtin_amdgcn_readfirstlane(__float_as_int(y))));
    t = __shfl_xor(y, 16);
    ysrc = takeT ? t : y;
  }
  // ---- owned range: W and W2 dots (shared rotations), loss, normalize ----
  float lossacc = 0.f;
  for (; s < n; ++s) {
    float ct = cts[w][s];
    float u  = exp2f(-ct * i2vl);
    ROTS(ysrc, a)
    DOT16(Wr, ysrc, a, pW)
    DOT16(Vr, ysrc, a, pV)
    float dotW = pW + __shfl_xor(pW, 32);
    float dotV = pV + __shfl_xor(pV, 32);
    float numj = u * dotW;
    float n2j  = (u * u) * dotV;
    float red  = h ? n2j : numj;
    RING16(red)
    red += __shfl_xor(red, 16);        // h=0 lanes: S ; h=1 lanes: N2
    float cross = __shfl_xor(red, 32);
    float S  = h ? cross : red;
    float N2 = h ? red   : cross;
    float rs = __builtin_amdgcn_rcpf(S);
    lossacc += N2 * rs;
    y = numj * rs;
    t = __shfl_xor(y, 16);
    ysrc = takeT ? t : y;
  }
  if (lane == 0) lossbuf[wv] = lossacc;
}

// ---------------------------------------------------------------------------
// Finish: sum NCH per-chunk losses -> out[0]
// ---------------------------------------------------------------------------
__global__ __launch_bounds__(256) void k_finish(const float* __restrict__ lb,
                                                float* __restrict__ out)
{
  const int tid = threadIdx.x;
  float v = 0.f;
  for (int l = tid; l < NCH; l += 256) v += lb[l];
#pragma unroll
  for (int o = 1; o < 64; o <<= 1) v += __shfl_xor(v, o);
  __shared__ float part[4];
  if ((tid & 63) == 0) part[tid >> 6] = v;
  __syncthreads();
  if (tid == 0) out[0] = part[0] + part[1] + part[2] + part[3];
}

extern "C" void kernel_launch(void* const* d_in, const int* in_sizes, int n_in,
                              void* d_out, int out_size, void* d_ws, size_t ws_size,
                              hipStream_t stream)
{
  (void)in_sizes; (void)n_in; (void)ws_size; (void)out_size;
  const float* obs2 = (const float*)d_in[0];
  const float* obs1 = (const float*)d_in[1];
  const float* mean = (const float*)d_in[2];
  const float* var  = (const float*)d_in[3];
  const float* bate = (const float*)d_in[4];
  const float* pi   = (const float*)d_in[5];
  const float* aij  = (const float*)d_in[6];
  float* lb  = (float*)d_ws;           // NCH floats, every slot written
  float* out = (float*)d_out;

  k_main  <<<NBLK, 256, 0, stream>>>(obs2, obs1, mean, var, bate, pi, aij, lb);
  k_finish<<<1,    256, 0, stream>>>(lb, out);
}